// Round 7
// baseline (149.859 us; speedup 1.0000x reference)
//
#include <hip/hip_runtime.h>

// (min,+) DP. TWO images per wave: chains A and B interleaved so each
// chain's dependency stalls (DPP hazards, trans latency, load latency) are
// filled by the other chain's independent instructions. 256 blocks = 1/CU.
// Depth-4-per-image rolling register prefetch with plain loads (compiler
// waitcnt protects all uses); sched_barrier(0) fences pin per-step order.

#define HH 256
#define WW 256
#define NULLV 1e30f

#define SBAR() __builtin_amdgcn_sched_barrier(0)

template<int CTRL, int ROWM>
__device__ __forceinline__ float dpp_mov(float x, float oldv) {
    return __builtin_bit_cast(float, __builtin_amdgcn_update_dpp(
        __builtin_bit_cast(int, oldv), __builtin_bit_cast(int, x),
        CTRL, ROWM, 0xF, false));
}

__device__ __forceinline__ float wave_iscan_add(float x) {
    x += dpp_mov<0x111, 0xF>(x, 0.0f);  // row_shr:1
    x += dpp_mov<0x112, 0xF>(x, 0.0f);  // row_shr:2
    x += dpp_mov<0x114, 0xF>(x, 0.0f);  // row_shr:4
    x += dpp_mov<0x118, 0xF>(x, 0.0f);  // row_shr:8
    x += dpp_mov<0x142, 0xA>(x, 0.0f);  // row_bcast:15 -> rows 1,3
    x += dpp_mov<0x143, 0xC>(x, 0.0f);  // row_bcast:31 -> rows 2,3
    return x;
}

__device__ __forceinline__ float wave_iscan_min(float x) {
    x = fminf(x, dpp_mov<0x111, 0xF>(x, NULLV));
    x = fminf(x, dpp_mov<0x112, 0xF>(x, NULLV));
    x = fminf(x, dpp_mov<0x114, 0xF>(x, NULLV));
    x = fminf(x, dpp_mov<0x118, 0xF>(x, NULLV));
    x = fminf(x, dpp_mov<0x142, 0xA>(x, NULLV));
    x = fminf(x, dpp_mov<0x143, 0xC>(x, NULLV));
    return x;
}

__device__ __forceinline__ float softplus_f(float x) {
    float ax = fabsf(x);
    float t  = __expf(-ax);
    return fmaxf(x, 0.0f) + __logf(1.0f + t);
}

struct Th { float S0, S1, S2, S3, soff; };

__device__ __forceinline__ Th prep(float4 c) {
    float th0 = softplus_f(c.x), th1 = softplus_f(c.y);
    float th2 = softplus_f(c.z), th3 = softplus_f(c.w);
    float t0 = th0, t1 = t0 + th1, t2 = t1 + th2, t3 = t2 + th3;
    float s    = wave_iscan_add(t3);
    float soff = dpp_mov<0x138, 0xF>(s, 0.0f);  // wave_shr:1, lane0 -> 0
    Th t;
    t.soff = soff;
    t.S0 = soff + t0; t.S1 = soff + t1; t.S2 = soff + t2; t.S3 = soff + t3;
    return t;
}

__device__ __forceinline__ void vchain(float& v0, float& v1, float& v2, float& v3,
                                       const Th& t) {
    float vm1 = dpp_mov<0x138, 0xF>(v3, NULLV);  // shift right one col
    float B0 = fminf(v0, vm1) - t.soff;
    float B1 = fminf(v1, v0) - t.S0;
    float B2 = fminf(v2, v1) - t.S1;
    float B3 = fminf(v3, v2) - t.S2;
    float m1 = fminf(B0, B1);
    float m2 = fminf(m1, B2);
    float m3 = fminf(m2, B3);
    float mm   = wave_iscan_min(m3);
    float moff = dpp_mov<0x138, 0xF>(mm, NULLV);
    v0 = t.S0 + fminf(moff, B0);
    v1 = t.S1 + fminf(moff, m1);
    v2 = t.S2 + fminf(moff, m2);
    v3 = t.S3 + fminf(moff, m3);
}

#define RI(r) ((size_t)(((r) < 255) ? (r) : 255) * 64)

__global__ __launch_bounds__(64, 1) void dp_kernel(const float* __restrict__ img,
                                                   float* __restrict__ out) {
    const int lane = threadIdx.x;
    const size_t ipix = (size_t)HH * WW;
    const float4* pa =
        reinterpret_cast<const float4*>(img + (size_t)(2 * blockIdx.x) * ipix) + lane;
    const float4* pb = pa + ipix / 4;  // next image

    // ring slot for row r is r & 3 (per image)
    float4 a0 = pa[RI(0)], a1 = pa[RI(1)], a2 = pa[RI(2)], a3 = pa[RI(3)];
    float4 b0 = pb[RI(0)], b1 = pb[RI(1)], b2 = pb[RI(2)], b3 = pb[RI(3)];
    SBAR();

    float vA0, vA1, vA2, vA3, vB0, vB1, vB2, vB3;
    { Th t = prep(a0); vA0 = t.S0; vA1 = t.S1; vA2 = t.S2; vA3 = t.S3; }
    { Th t = prep(b0); vB0 = t.S0; vB1 = t.S1; vB2 = t.S2; vB3 = t.S3; }
    a0 = pa[RI(4)]; b0 = pb[RI(4)];
    SBAR();
    Th tCA = prep(a1), tCB = prep(b1), tNA, tNB;
    a1 = pa[RI(5)]; b1 = pb[RI(5)];
    SBAR();

    // STEP(slotA, slotB, loadrow): vchain current row (tC), prep next row
    // from slot, refill slot with loadrow. One ring rotation of lead time.
#define STEP(sa, sb, ldr)                                        \
    tNA = prep(sa); tNB = prep(sb);                              \
    vchain(vA0, vA1, vA2, vA3, tCA);                             \
    vchain(vB0, vB1, vB2, vB3, tCB);                             \
    sa = pa[RI(ldr)]; sb = pb[RI(ldr)];                          \
    SBAR();                                                      \
    tCA = tNA; tCB = tNB;

    // 63 chunks x 4 rows: vchain rows 1..252
#pragma unroll 1
    for (int c = 0; c < 63; ++c) {
        const int rb = 4 * c;
        STEP(a2, b2, rb + 6)
        STEP(a3, b3, rb + 7)
        STEP(a0, b0, rb + 8)
        STEP(a1, b1, rb + 9)
    }

    // epilogue: rows 253..255 (slot2 holds row 254, slot3 holds row 255)
    tNA = prep(a2); tNB = prep(b2);
    vchain(vA0, vA1, vA2, vA3, tCA); vchain(vB0, vB1, vB2, vB3, tCB);
    tCA = tNA; tCB = tNB;                       // row 253 done
    tNA = prep(a3); tNB = prep(b3);
    vchain(vA0, vA1, vA2, vA3, tCA); vchain(vB0, vB1, vB2, vB3, tCB);
    tCA = tNA; tCB = tNB;                       // row 254 done
    vchain(vA0, vA1, vA2, vA3, tCA); vchain(vB0, vB1, vB2, vB3, tCB);  // row 255

    if (lane == 63) {
        out[2 * blockIdx.x]     = vA3;
        out[2 * blockIdx.x + 1] = vB3;
    }
}

extern "C" void kernel_launch(void* const* d_in, const int* in_sizes, int n_in,
                              void* d_out, int out_size, void* d_ws, size_t ws_size,
                              hipStream_t stream) {
    const float* img = (const float*)d_in[0];
    float* out = (float*)d_out;
    dp_kernel<<<out_size / 2, 64, 0, stream>>>(img, out);
}

// Round 8
// 142.068 us; speedup vs baseline: 1.0548x; 1.0548x over previous
//
#include <hip/hip_runtime.h>

// (min,+) DP, one wave per image (H=W=256, lane owns 4 contiguous cols).
// Staging via global_load_lds ring (8 rows x 1KB): the intrinsic has NO VGPR
// destination, so the register allocator cannot sink/copy the prefetch (the
// failure mode of R2-R6). Counted s_waitcnt vmcnt(7) per row = 8 rows of
// lead; ds_read_b128 from LDS is compiler-owned (precise lgkm waits).
// Cross-lane via DPP. prep(r+1) interleaved with vchain(r).

#define HH 256
#define WW 256
#define NULLV 1e30f

#define SBAR() __builtin_amdgcn_sched_barrier(0)
#define WAITVM(n) do {                                      \
    asm volatile("s_waitcnt vmcnt(" #n ")" ::: "memory");   \
    __builtin_amdgcn_sched_barrier(0);                      \
} while (0)

template<int CTRL, int ROWM>
__device__ __forceinline__ float dpp_mov(float x, float oldv) {
    return __builtin_bit_cast(float, __builtin_amdgcn_update_dpp(
        __builtin_bit_cast(int, oldv), __builtin_bit_cast(int, x),
        CTRL, ROWM, 0xF, false));
}

__device__ __forceinline__ float wave_iscan_add(float x) {
    x += dpp_mov<0x111, 0xF>(x, 0.0f);  // row_shr:1
    x += dpp_mov<0x112, 0xF>(x, 0.0f);  // row_shr:2
    x += dpp_mov<0x114, 0xF>(x, 0.0f);  // row_shr:4
    x += dpp_mov<0x118, 0xF>(x, 0.0f);  // row_shr:8
    x += dpp_mov<0x142, 0xA>(x, 0.0f);  // row_bcast:15 -> rows 1,3
    x += dpp_mov<0x143, 0xC>(x, 0.0f);  // row_bcast:31 -> rows 2,3
    return x;
}

__device__ __forceinline__ float wave_iscan_min(float x) {
    x = fminf(x, dpp_mov<0x111, 0xF>(x, NULLV));
    x = fminf(x, dpp_mov<0x112, 0xF>(x, NULLV));
    x = fminf(x, dpp_mov<0x114, 0xF>(x, NULLV));
    x = fminf(x, dpp_mov<0x118, 0xF>(x, NULLV));
    x = fminf(x, dpp_mov<0x142, 0xA>(x, NULLV));
    x = fminf(x, dpp_mov<0x143, 0xC>(x, NULLV));
    return x;
}

__device__ __forceinline__ float softplus_f(float x) {
    float ax = fabsf(x);
    float t  = __expf(-ax);
    return fmaxf(x, 0.0f) + __logf(1.0f + t);
}

struct Th { float S0, S1, S2, S3, soff; };

__device__ __forceinline__ Th prep(float4 c) {
    float th0 = softplus_f(c.x), th1 = softplus_f(c.y);
    float th2 = softplus_f(c.z), th3 = softplus_f(c.w);
    float t0 = th0, t1 = t0 + th1, t2 = t1 + th2, t3 = t2 + th3;
    float s    = wave_iscan_add(t3);
    float soff = dpp_mov<0x138, 0xF>(s, 0.0f);  // wave_shr:1, lane0 -> 0
    Th t;
    t.soff = soff;
    t.S0 = soff + t0; t.S1 = soff + t1; t.S2 = soff + t2; t.S3 = soff + t3;
    return t;
}

// async global->LDS, 16B per lane; dest = wave-uniform base + lane*16
__device__ __forceinline__ void stage_row(const float* gp, float* lp) {
    __builtin_amdgcn_global_load_lds(
        (const __attribute__((address_space(1))) void*)gp,
        (__attribute__((address_space(3))) void*)lp,
        16, 0, 0);
}

__global__ __launch_bounds__(64, 1) void dp_kernel(const float* __restrict__ img,
                                                   float* __restrict__ out) {
    const int lane = threadIdx.x;
    // per-lane global src: lane*16B within a 1KB row
    const float* g = img + (size_t)blockIdx.x * HH * WW + (size_t)lane * 4;

    __shared__ __align__(16) float ring[8][WW];  // 8 rows x 1KB

    float v0, v1, v2, v3;

    auto vchain = [&](const Th& t) {
        float vm1 = dpp_mov<0x138, 0xF>(v3, NULLV);  // shift right one col
        float B0 = fminf(v0, vm1) - t.soff;
        float B1 = fminf(v1, v0) - t.S0;
        float B2 = fminf(v2, v1) - t.S1;
        float B3 = fminf(v3, v2) - t.S2;
        float m1 = fminf(B0, B1);
        float m2 = fminf(m1, B2);
        float m3 = fminf(m2, B3);
        float mm   = wave_iscan_min(m3);
        float moff = dpp_mov<0x138, 0xF>(mm, NULLV);
        v0 = t.S0 + fminf(moff, B0);
        v1 = t.S1 + fminf(moff, m1);
        v2 = t.S2 + fminf(moff, m2);
        v3 = t.S3 + fminf(moff, m3);
    };

    auto rd = [&](int slot) -> float4 {
        return *reinterpret_cast<const float4*>(&ring[slot][lane * 4]);
    };

    // ---- prologue: stage rows 0..7 ----
    stage_row(g + 0 * WW, &ring[0][0]); stage_row(g + 1 * WW, &ring[1][0]);
    stage_row(g + 2 * WW, &ring[2][0]); stage_row(g + 3 * WW, &ring[3][0]);
    stage_row(g + 4 * WW, &ring[4][0]); stage_row(g + 5 * WW, &ring[5][0]);
    stage_row(g + 6 * WW, &ring[6][0]); stage_row(g + 7 * WW, &ring[7][0]);

    WAITVM(7);                          // row 0 staged
    { Th t = prep(rd(0)); v0 = t.S0; v1 = t.S1; v2 = t.S2; v3 = t.S3; }
    stage_row(g + 8 * WW, &ring[0][0]); // rows 1..8 outstanding
    WAITVM(7);                          // row 1 staged
    Th tC = prep(rd(1)), tN;
    SBAR();

    // ---- main: rows 1..247 chained; stage row r+8; 8 in flight ----
#pragma unroll 1
    for (int r = 1; r <= 247; ++r) {
        stage_row(g + (size_t)(r + 8) * WW, &ring[(r + 8) & 7][0]);
        WAITVM(7);                      // row r+1 staged
        tN = prep(rd((r + 1) & 7));
        vchain(tC);                     // row r
        tC = tN;
        SBAR();
    }

    // ---- epilogue: rows 248..255; drain counted waits 6..0 ----
#define EPI(r, n) do {                                   \
        WAITVM(n);                                       \
        tN = prep(rd((r + 1) & 7));                      \
        vchain(tC); tC = tN; SBAR();                     \
    } while (0)
    EPI(248, 6); EPI(249, 5); EPI(250, 4); EPI(251, 3);
    EPI(252, 2); EPI(253, 1); EPI(254, 0);
    vchain(tC);                         // row 255
#undef EPI

    if (lane == 63) out[blockIdx.x] = v3;
}

extern "C" void kernel_launch(void* const* d_in, const int* in_sizes, int n_in,
                              void* d_out, int out_size, void* d_ws, size_t ws_size,
                              hipStream_t stream) {
    const float* img = (const float*)d_in[0];
    float* out = (float*)d_out;
    dp_kernel<<<out_size, 64, 0, stream>>>(img, out);
}

// Round 9
// 66.311 us; speedup vs baseline: 2.2599x; 2.1425x over previous
//
#include <hip/hip_runtime.h>

// (min,+) DP with wave specialization. 5 waves/block per image:
//   waves 1-4: prep = softplus + row-cumsum S for a 32-row chunk -> LDS
//              (row-independent work, 75% of the instructions)
//   wave 0:    the serial vchain recurrence, one ds_read_b128 per row;
//              soff (=S[4l-1]) derived from S.w via DPP wave_shr:1.
// Double-buffered 2x32x1KB LDS chunks, 8 __syncthreads per image.
// Cross-lane via DPP only.

#define HH 256
#define WW 256
#define CH 32          // rows per chunk
#define NCH 8          // chunks per image
#define NULLV 1e30f

template<int CTRL, int ROWM>
__device__ __forceinline__ float dpp_mov(float x, float oldv) {
    return __builtin_bit_cast(float, __builtin_amdgcn_update_dpp(
        __builtin_bit_cast(int, oldv), __builtin_bit_cast(int, x),
        CTRL, ROWM, 0xF, false));
}

__device__ __forceinline__ float wave_iscan_add(float x) {
    x += dpp_mov<0x111, 0xF>(x, 0.0f);  // row_shr:1
    x += dpp_mov<0x112, 0xF>(x, 0.0f);  // row_shr:2
    x += dpp_mov<0x114, 0xF>(x, 0.0f);  // row_shr:4
    x += dpp_mov<0x118, 0xF>(x, 0.0f);  // row_shr:8
    x += dpp_mov<0x142, 0xA>(x, 0.0f);  // row_bcast:15 -> rows 1,3
    x += dpp_mov<0x143, 0xC>(x, 0.0f);  // row_bcast:31 -> rows 2,3
    return x;
}

__device__ __forceinline__ float wave_iscan_min(float x) {
    x = fminf(x, dpp_mov<0x111, 0xF>(x, NULLV));
    x = fminf(x, dpp_mov<0x112, 0xF>(x, NULLV));
    x = fminf(x, dpp_mov<0x114, 0xF>(x, NULLV));
    x = fminf(x, dpp_mov<0x118, 0xF>(x, NULLV));
    x = fminf(x, dpp_mov<0x142, 0xA>(x, NULLV));
    x = fminf(x, dpp_mov<0x143, 0xC>(x, NULLV));
    return x;
}

__device__ __forceinline__ float softplus_f(float x) {
    float ax = fabsf(x);
    float t  = __expf(-ax);
    return fmaxf(x, 0.0f) + __logf(1.0f + t);
}

// full-row cumsum of softplus for one row; returns S at cols 4l..4l+3
__device__ __forceinline__ float4 prep_row(float4 c) {
    float t0 = softplus_f(c.x);
    float t1 = t0 + softplus_f(c.y);
    float t2 = t1 + softplus_f(c.z);
    float t3 = t2 + softplus_f(c.w);
    float s    = wave_iscan_add(t3);
    float soff = dpp_mov<0x138, 0xF>(s, 0.0f);  // wave_shr:1, lane0 -> 0
    return make_float4(soff + t0, soff + t1, soff + t2, soff + t3);
}

__global__ __launch_bounds__(320, 1) void dp_kernel(const float* __restrict__ img,
                                                    float* __restrict__ out) {
    const int tid = threadIdx.x;
    const int wid = tid >> 6;      // 0 = chain wave, 1..4 = prep waves
    const int lane = tid & 63;

    __shared__ __align__(16) float sbuf[2][CH][WW];   // 64 KB double buffer

    const float* gbase = img + (size_t)blockIdx.x * HH * WW;

    if (wid == 0) {
        // ---------------- chain wave ----------------
        float v0 = 0.f, v1 = 0.f, v2 = 0.f, v3 = 0.f;
        for (int k = 0; k < NCH; ++k) {
            __syncthreads();                       // chunk k ready in sbuf[k&1]
            const float(*buf)[WW] = sbuf[k & 1];
            float4 S = *reinterpret_cast<const float4*>(&buf[0][lane * 4]);
#pragma unroll 4
            for (int i = 0; i < CH; ++i) {
                const int ip = (i + 1 < CH) ? i + 1 : i;
                float4 Sn = *reinterpret_cast<const float4*>(&buf[ip][lane * 4]);
                if (k == 0 && i == 0) {
                    v0 = S.x; v1 = S.y; v2 = S.z; v3 = S.w;   // row 0 init
                } else {
                    float soff = dpp_mov<0x138, 0xF>(S.w, 0.0f); // S[4l-1]
                    float vm1  = dpp_mov<0x138, 0xF>(v3, NULLV); // v[4l-1]
                    float B0 = fminf(v0, vm1) - soff;
                    float B1 = fminf(v1, v0) - S.x;
                    float B2 = fminf(v2, v1) - S.y;
                    float B3 = fminf(v3, v2) - S.z;
                    float m1 = fminf(B0, B1);
                    float m2 = fminf(m1, B2);
                    float m3 = fminf(m2, B3);
                    float mm   = wave_iscan_min(m3);
                    float moff = dpp_mov<0x138, 0xF>(mm, NULLV);
                    v0 = S.x + fminf(moff, B0);
                    v1 = S.y + fminf(moff, m1);
                    v2 = S.z + fminf(moff, m2);
                    v3 = S.w + fminf(moff, m3);
                }
                S = Sn;
            }
        }
        if (lane == 63) out[blockIdx.x] = v3;
    } else {
        // ---------------- prep waves ----------------
        const int pw = wid - 1;                    // 0..3
        const float4* gp = reinterpret_cast<const float4*>(gbase) + lane;
        for (int k = 0; k < NCH; ++k) {
            float(*buf)[WW] = sbuf[k & 1];
            const int rbase = k * CH + pw * 8;     // 8 rows per prep wave
            // issue all 8 row loads up front (independent, coalesced 1KB each)
            float4 L0 = gp[(size_t)(rbase + 0) * 64];
            float4 L1 = gp[(size_t)(rbase + 1) * 64];
            float4 L2 = gp[(size_t)(rbase + 2) * 64];
            float4 L3 = gp[(size_t)(rbase + 3) * 64];
            float4 L4 = gp[(size_t)(rbase + 4) * 64];
            float4 L5 = gp[(size_t)(rbase + 5) * 64];
            float4 L6 = gp[(size_t)(rbase + 6) * 64];
            float4 L7 = gp[(size_t)(rbase + 7) * 64];
            const int lb = pw * 8;
            *reinterpret_cast<float4*>(&buf[lb + 0][lane * 4]) = prep_row(L0);
            *reinterpret_cast<float4*>(&buf[lb + 1][lane * 4]) = prep_row(L1);
            *reinterpret_cast<float4*>(&buf[lb + 2][lane * 4]) = prep_row(L2);
            *reinterpret_cast<float4*>(&buf[lb + 3][lane * 4]) = prep_row(L3);
            *reinterpret_cast<float4*>(&buf[lb + 4][lane * 4]) = prep_row(L4);
            *reinterpret_cast<float4*>(&buf[lb + 5][lane * 4]) = prep_row(L5);
            *reinterpret_cast<float4*>(&buf[lb + 6][lane * 4]) = prep_row(L6);
            *reinterpret_cast<float4*>(&buf[lb + 7][lane * 4]) = prep_row(L7);
            __syncthreads();                       // publish chunk k
        }
    }
}

extern "C" void kernel_launch(void* const* d_in, const int* in_sizes, int n_in,
                              void* d_out, int out_size, void* d_ws, size_t ws_size,
                              hipStream_t stream) {
    const float* img = (const float*)d_in[0];
    float* out = (float*)d_out;
    dp_kernel<<<out_size, 320, 0, stream>>>(img, out);
}

// Round 10
// 58.560 us; speedup vs baseline: 2.5591x; 1.1324x over previous
//
#include <hip/hip_runtime.h>

// (min,+) DP with wave specialization. 5 waves/block per image:
//   waves 1-4: prep = softplus + row-cumsum S for a 16-row chunk -> LDS
//   wave 0:    serial vchain recurrence; S prefetched 2 rows ahead in regs.
// CH=16 keeps LDS at 2x16KB=32KB so TWO blocks/CU co-reside (R9's 64KB
// allowed only one -> grid ran as 2 sequential rounds; occupancy 13.9%).

#define HH 256
#define WW 256
#define CH 16          // rows per chunk
#define NCH 16         // chunks per image
#define NULLV 1e30f

template<int CTRL, int ROWM>
__device__ __forceinline__ float dpp_mov(float x, float oldv) {
    return __builtin_bit_cast(float, __builtin_amdgcn_update_dpp(
        __builtin_bit_cast(int, oldv), __builtin_bit_cast(int, x),
        CTRL, ROWM, 0xF, false));
}

__device__ __forceinline__ float wave_iscan_add(float x) {
    x += dpp_mov<0x111, 0xF>(x, 0.0f);  // row_shr:1
    x += dpp_mov<0x112, 0xF>(x, 0.0f);  // row_shr:2
    x += dpp_mov<0x114, 0xF>(x, 0.0f);  // row_shr:4
    x += dpp_mov<0x118, 0xF>(x, 0.0f);  // row_shr:8
    x += dpp_mov<0x142, 0xA>(x, 0.0f);  // row_bcast:15 -> rows 1,3
    x += dpp_mov<0x143, 0xC>(x, 0.0f);  // row_bcast:31 -> rows 2,3
    return x;
}

__device__ __forceinline__ float wave_iscan_min(float x) {
    x = fminf(x, dpp_mov<0x111, 0xF>(x, NULLV));
    x = fminf(x, dpp_mov<0x112, 0xF>(x, NULLV));
    x = fminf(x, dpp_mov<0x114, 0xF>(x, NULLV));
    x = fminf(x, dpp_mov<0x118, 0xF>(x, NULLV));
    x = fminf(x, dpp_mov<0x142, 0xA>(x, NULLV));
    x = fminf(x, dpp_mov<0x143, 0xC>(x, NULLV));
    return x;
}

__device__ __forceinline__ float softplus_f(float x) {
    float ax = fabsf(x);
    float t  = __expf(-ax);
    return fmaxf(x, 0.0f) + __logf(1.0f + t);
}

// full-row cumsum of softplus for one row; returns S at cols 4l..4l+3
__device__ __forceinline__ float4 prep_row(float4 c) {
    float t0 = softplus_f(c.x);
    float t1 = t0 + softplus_f(c.y);
    float t2 = t1 + softplus_f(c.z);
    float t3 = t2 + softplus_f(c.w);
    float s    = wave_iscan_add(t3);
    float soff = dpp_mov<0x138, 0xF>(s, 0.0f);  // wave_shr:1, lane0 -> 0
    return make_float4(soff + t0, soff + t1, soff + t2, soff + t3);
}

__global__ __launch_bounds__(320, 2) void dp_kernel(const float* __restrict__ img,
                                                    float* __restrict__ out) {
    const int tid = threadIdx.x;
    const int wid = tid >> 6;      // 0 = chain wave, 1..4 = prep waves
    const int lane = tid & 63;

    __shared__ __align__(16) float sbuf[2][CH][WW];   // 32 KB double buffer

    const float* gbase = img + (size_t)blockIdx.x * HH * WW;

    if (wid == 0) {
        // ---------------- chain wave ----------------
        float v0, v1, v2, v3;

        auto row_step = [&](const float4& S) {
            float soff = dpp_mov<0x138, 0xF>(S.w, 0.0f);  // S[4l-1]
            float vm1  = dpp_mov<0x138, 0xF>(v3, NULLV);  // v[4l-1]
            float B0 = fminf(v0, vm1) - soff;
            float B1 = fminf(v1, v0) - S.x;
            float B2 = fminf(v2, v1) - S.y;
            float B3 = fminf(v3, v2) - S.z;
            float m1 = fminf(B0, B1);
            float m2 = fminf(m1, B2);
            float m3 = fminf(m2, B3);
            float mm   = wave_iscan_min(m3);
            float moff = dpp_mov<0x138, 0xF>(mm, NULLV);
            v0 = S.x + fminf(moff, B0);
            v1 = S.y + fminf(moff, m1);
            v2 = S.z + fminf(moff, m2);
            v3 = S.w + fminf(moff, m3);
        };

#define RD(buf, i) (*reinterpret_cast<const float4*>(&(buf)[i][lane * 4]))

        // chunk 0 (peel row-0 init)
        __syncthreads();
        {
            const float(*buf)[WW] = sbuf[0];
            float4 S0r = RD(buf, 0);
            v0 = S0r.x; v1 = S0r.y; v2 = S0r.z; v3 = S0r.w;
            float4 Sc = RD(buf, 1), Sn = RD(buf, 2);
#pragma unroll
            for (int i = 1; i < CH; ++i) {
                float4 Sn2 = (i + 2 < CH) ? RD(buf, i + 2) : Sn;
                row_step(Sc);
                Sc = Sn; Sn = Sn2;
            }
        }
        // chunks 1..15
        for (int k = 1; k < NCH; ++k) {
            __syncthreads();
            const float(*buf)[WW] = sbuf[k & 1];
            float4 Sc = RD(buf, 0), Sn = RD(buf, 1);
#pragma unroll
            for (int i = 0; i < CH; ++i) {
                float4 Sn2 = (i + 2 < CH) ? RD(buf, i + 2) : Sn;
                row_step(Sc);
                Sc = Sn; Sn = Sn2;
            }
        }
#undef RD
        if (lane == 63) out[blockIdx.x] = v3;
    } else {
        // ---------------- prep waves ----------------
        const int pw = wid - 1;                    // 0..3, 4 rows each
        const float4* gp = reinterpret_cast<const float4*>(gbase) + lane;
        for (int k = 0; k < NCH; ++k) {
            float(*buf)[WW] = sbuf[k & 1];
            const int rbase = k * CH + pw * 4;
            float4 L0 = gp[(size_t)(rbase + 0) * 64];
            float4 L1 = gp[(size_t)(rbase + 1) * 64];
            float4 L2 = gp[(size_t)(rbase + 2) * 64];
            float4 L3 = gp[(size_t)(rbase + 3) * 64];
            const int lb = pw * 4;
            *reinterpret_cast<float4*>(&buf[lb + 0][lane * 4]) = prep_row(L0);
            *reinterpret_cast<float4*>(&buf[lb + 1][lane * 4]) = prep_row(L1);
            *reinterpret_cast<float4*>(&buf[lb + 2][lane * 4]) = prep_row(L2);
            *reinterpret_cast<float4*>(&buf[lb + 3][lane * 4]) = prep_row(L3);
            __syncthreads();                       // publish chunk k
        }
    }
}

extern "C" void kernel_launch(void* const* d_in, const int* in_sizes, int n_in,
                              void* d_out, int out_size, void* d_ws, size_t ws_size,
                              hipStream_t stream) {
    const float* img = (const float*)d_in[0];
    float* out = (float*)d_out;
    dp_kernel<<<out_size, 320, 0, stream>>>(img, out);
}